// Round 14
// baseline (195.739 us; speedup 1.0000x reference)
//
#include <hip/hip_runtime.h>

typedef __bf16 bf16;
typedef __attribute__((ext_vector_type(8))) __bf16 bf16x8;
typedef __attribute__((ext_vector_type(4))) __bf16 bf16x4;
typedef __attribute__((ext_vector_type(4))) float f32x4;

constexpr int T_SEQ = 2048;
constexpr int DIM   = 2048;
constexpr int NH    = 32;
constexpr int NKV   = 8;
constexpr int HD    = 64;
constexpr int QKV_N = DIM + 2 * NKV * HD;   // 3072
constexpr int MROWS = 2 * T_SEQ;            // 4096 (B*T)

// ---------------- cast f32 -> bf16 (x) ----------------
__global__ void cast_kernel(const float* __restrict__ in, bf16* __restrict__ out, int n) {
  int stride = gridDim.x * blockDim.x * 4;
  for (int i = (blockIdx.x * blockDim.x + threadIdx.x) * 4; i < n; i += stride) {
    float4 v = *(const float4*)(in + i);
    bf16x4 o = { (bf16)v.x, (bf16)v.y, (bf16)v.z, (bf16)v.w };
    *(bf16x4*)(out + i) = o;
  }
}

// ---------------- fused weight cast: wq|wk|wv -> wqkv, wo -> wob ----------------
__global__ void cast_w_kernel(const float* __restrict__ wq, const float* __restrict__ wk,
                              const float* __restrict__ wv, const float* __restrict__ wo,
                              bf16* __restrict__ wqkv, bf16* __restrict__ wob) {
  int stride = gridDim.x * blockDim.x;
  for (int g = blockIdx.x * blockDim.x + threadIdx.x; g < 2621440; g += stride) {
    const float* src; bf16* dst; int off;
    if (g < 1048576)      { src = wq; dst = wqkv;           off = g; }
    else if (g < 1310720) { src = wk; dst = wqkv + 4194304; off = g - 1048576; }
    else if (g < 1572864) { src = wv; dst = wqkv + 5242880; off = g - 1310720; }
    else                  { src = wo; dst = wob;            off = g - 1572864; }
    float4 v = *(const float4*)(src + (size_t)off * 4);
    bf16x4 o = { (bf16)v.x, (bf16)v.y, (bf16)v.z, (bf16)v.w };
    *(bf16x4*)(dst + (size_t)off * 4) = o;
  }
}

// ---------------- GEMM (unchanged R11: 3-deep ring, counted vmcnt(6)) ----------------
template <typename OutT>
__global__ __launch_bounds__(512) void gemm256(const bf16* __restrict__ A,
                                               const bf16* __restrict__ W,
                                               OutT* __restrict__ C,
                                               int N, int K, int cpx) {
  constexpr int BM = 256, BN = 128, BK = 64;
  __shared__ __attribute__((aligned(16))) bf16 Ab[3][BM * BK];
  __shared__ __attribute__((aligned(16))) bf16 Bb[3][BN * BK];
  const int tid = threadIdx.x, lane = tid & 63, wave = tid >> 6;
  const int l15 = lane & 15, l4 = lane >> 4;
  const int orig = blockIdx.x;
  const int wg = (orig & 7) * cpx + (orig >> 3);
  const int bm = (wg & 15) * BM;
  const int bn = (wg >> 4) * BN;
  const int wm = (wave >> 1) * 64, wn = (wave & 1) * 64;

  f32x4 acc[4][4] = {};

  const int NT = K / BK;
  auto stage = [&](int s, int k0) {
    #pragma unroll
    for (int i = 0; i < 4; ++i) {
      int c = i * 512 + tid;
      int row = c >> 3;
      int gc = ((c & 7) ^ (row & 7)) << 3;
      __builtin_amdgcn_global_load_lds(
          (const __attribute__((address_space(1))) unsigned int*)(A + (size_t)(bm + row) * K + k0 + gc),
          (__attribute__((address_space(3))) unsigned int*)(&Ab[s][0] + c * 8), 16, 0, 0);
    }
    #pragma unroll
    for (int i = 0; i < 2; ++i) {
      int c = i * 512 + tid;
      int row = c >> 3;
      int gc = ((c & 7) ^ (row & 7)) << 3;
      __builtin_amdgcn_global_load_lds(
          (const __attribute__((address_space(1))) unsigned int*)(W + (size_t)(bn + row) * K + k0 + gc),
          (__attribute__((address_space(3))) unsigned int*)(&Bb[s][0] + c * 8), 16, 0, 0);
    }
  };

  stage(0, 0);
  stage(1, BK);

  int d = 0;
  for (int t = 0; t < NT; ++t) {
    if (t + 1 < NT) { asm volatile("s_waitcnt vmcnt(6)" ::: "memory"); }
    else            { asm volatile("s_waitcnt vmcnt(0)" ::: "memory"); }
    __builtin_amdgcn_s_barrier();

    bf16x8 af[2][4], bfr[2][4];
    #pragma unroll
    for (int kk = 0; kk < 2; ++kk) {
      #pragma unroll
      for (int mi = 0; mi < 4; ++mi) {
        int row = wm + mi * 16 + l15;
        af[kk][mi] = *(const bf16x8*)((const char*)&Ab[d][0] + row * 128 +
                                      (((kk * 4 + l4) ^ (row & 7)) << 4));
      }
      #pragma unroll
      for (int ni = 0; ni < 4; ++ni) {
        int row = wn + ni * 16 + l15;
        bfr[kk][ni] = *(const bf16x8*)((const char*)&Bb[d][0] + row * 128 +
                                       (((kk * 4 + l4) ^ (row & 7)) << 4));
      }
    }

    if (t + 2 < NT) {
      int s = d + 2; if (s >= 3) s -= 3;
      stage(s, (t + 2) * BK);
    }

    __builtin_amdgcn_s_setprio(1);
    #pragma unroll
    for (int kk = 0; kk < 2; ++kk)
      #pragma unroll
      for (int mi = 0; mi < 4; ++mi)
        #pragma unroll
        for (int ni = 0; ni < 4; ++ni)
          acc[mi][ni] = __builtin_amdgcn_mfma_f32_16x16x32_bf16(af[kk][mi], bfr[kk][ni],
                                                                acc[mi][ni], 0, 0, 0);
    __builtin_amdgcn_s_setprio(0);

    ++d; if (d == 3) d = 0;
  }

  #pragma unroll
  for (int mi = 0; mi < 4; ++mi)
    #pragma unroll
    for (int ni = 0; ni < 4; ++ni) {
      size_t row = (size_t)bm + wm + mi * 16 + l4 * 4;
      int col = bn + wn + ni * 16 + l15;
      #pragma unroll
      for (int r = 0; r < 4; ++r)
        C[(row + r) * N + col] = (OutT)acc[mi][ni][r];
    }
}

// ---------------- RoPE, vectorized (unchanged) ----------------
__global__ void rope_kernel(bf16* __restrict__ qkv, const float* __restrict__ cs,
                            const float* __restrict__ sn) {
  int idx = blockIdx.x * blockDim.x + threadIdx.x;
  int m = idx / 160;
  int ch = idx - m * 160;
  int t = m & (T_SEQ - 1);
  int col, c;
  if (ch < 128) { int hh = ch >> 2; c = ch & 3; col = hh * 64 + c * 16; }
  else          { int ch2 = ch - 128; int hh = ch2 >> 2; c = ch2 & 3; col = DIM + hh * 64 + c * 16; }
  bf16* ptr = qkv + (size_t)m * QKV_N + col;
  bf16x8 v0 = *(bf16x8*)ptr, v1 = *(bf16x8*)(ptr + 8);
  const float* cp = cs + t * 32 + c * 8;
  const float* sp = sn + t * 32 + c * 8;
  float4 c0 = *(const float4*)cp, c1 = *(const float4*)(cp + 4);
  float4 s0 = *(const float4*)sp, s1 = *(const float4*)(sp + 4);
  float cc[8] = {c0.x, c0.y, c0.z, c0.w, c1.x, c1.y, c1.z, c1.w};
  float ss[8] = {s0.x, s0.y, s0.z, s0.w, s1.x, s1.y, s1.z, s1.w};
  bf16x8 o0, o1;
  #pragma unroll
  for (int j = 0; j < 4; ++j) {
    float a = (float)v0[2 * j], b = (float)v0[2 * j + 1];
    o0[2 * j]     = (bf16)(a * cc[j] - b * ss[j]);
    o0[2 * j + 1] = (bf16)(a * ss[j] + b * cc[j]);
  }
  #pragma unroll
  for (int j = 0; j < 4; ++j) {
    float a = (float)v1[2 * j], b = (float)v1[2 * j + 1];
    o1[2 * j]     = (bf16)(a * cc[4 + j] - b * ss[4 + j]);
    o1[2 * j + 1] = (bf16)(a * ss[4 + j] + b * cc[4 + j]);
  }
  *(bf16x8*)ptr = o0;
  *(bf16x8*)(ptr + 8) = o1;
}

// ---------------- Flash attention, causal GQA ----------------
// grid (NH, 8, B); 512 thr = 8 waves x 16 q-rows. Each block processes TWO
// strips sequentially: hi = 15-p then lo = p -> every block = exactly 34
// staged tiles (uniform makespan; fixes the mean/max=50% utilization of the
// one-strip-per-block grid where all blocks were co-resident with no backfill).
// 40KB LDS -> 2 blocks/CU resident (512 blocks total), all finish together.
__global__ __launch_bounds__(512, 4) void attn_kernel(const bf16* __restrict__ qkv,
                                                      bf16* __restrict__ y) {
  const int h = blockIdx.x, b = blockIdx.z;
  const int p = blockIdx.y;                       // pair index 0..7
  const int g = h >> 2;
  const int tid = threadIdx.x, lane = tid & 63, wave = tid >> 6;
  const int l15 = lane & 15, l4 = lane >> 4;

  __shared__ __attribute__((aligned(16))) bf16 Kb[2][64 * 64];   // [kv][d], swizzled, dbuf
  __shared__ __attribute__((aligned(16))) bf16 VTs[64 * 64];     // [d][kv], swizzled, single
  __shared__ __attribute__((aligned(16))) bf16 Pb[8][16 * 64];   // per-wave [q][kv], swizzled

  constexpr float SCALE2 = 0.125f * 1.44269504088896f;
  constexpr float THR_RAW = 8.0f / SCALE2;
  const size_t kvbase = (size_t)b * T_SEQ;

  #pragma unroll
  for (int sp = 0; sp < 2; ++sp) {
    const int strip = sp == 0 ? (15 - p) : p;
    const int qbase = strip * 128 + wave * 16;
    const int last_kt = (qbase + 15) >> 6;
    const int nt_loop = 2 * strip + 2;

    __syncthreads();   // retire previous strip's Kb/VTs readers

    // Q fragments (B-operand of swapped QK^T): rows qbase+l15
    bf16x8 qf[2];
    {
      const bf16* qp = qkv + ((size_t)b * T_SEQ + qbase + l15) * QKV_N + h * HD + l4 * 8;
      qf[0] = *(const bf16x8*)(qp);
      qf[1] = *(const bf16x8*)(qp + 32);
    }

    f32x4 oacc[4] = {};
    float m_run = -INFINITY, l_run = 0.f;

    // ---- prologue: K0 glds -> Kb[0]; V0 gather -> VTs ----
    {
      int r = tid >> 3;
      int csrc = ((tid & 7) << 3) ^ ((r & 7) << 3);
      __builtin_amdgcn_global_load_lds(
          (const __attribute__((address_space(1))) unsigned int*)
              (qkv + (kvbase + r) * QKV_N + DIM + g * HD + csrc),
          (__attribute__((address_space(3))) unsigned int*)(&Kb[0][0] + tid * 8), 16, 0, 0);
      const bf16* vp = qkv + (kvbase + wave * 8) * QKV_N + DIM + NKV * HD + g * HD + lane;
      bf16x8 vr;
      #pragma unroll
      for (int j = 0; j < 8; ++j) vr[j] = vp[(size_t)j * QKV_N];
      *(bf16x8*)((char*)&VTs[0] + ((lane * 128 + wave * 16) ^ ((lane & 7) << 4))) = vr;
      asm volatile("s_waitcnt vmcnt(0)" ::: "memory");
      __syncthreads();
    }

    int cur = 0;
    for (int kt = 0; kt < nt_loop; ++kt) {
      const bool has_next = (kt + 1) < nt_loop;
      bf16x8 vr;
      if (has_next) {
        int r = tid >> 3;
        int csrc = ((tid & 7) << 3) ^ ((r & 7) << 3);
        __builtin_amdgcn_global_load_lds(
            (const __attribute__((address_space(1))) unsigned int*)
                (qkv + (kvbase + (kt + 1) * 64 + r) * QKV_N + DIM + g * HD + csrc),
            (__attribute__((address_space(3))) unsigned int*)(&Kb[cur ^ 1][0] + tid * 8), 16, 0, 0);
        const bf16* vp = qkv + (kvbase + (kt + 1) * 64 + wave * 8) * QKV_N
                             + DIM + NKV * HD + g * HD + lane;
        #pragma unroll
        for (int j = 0; j < 8; ++j) vr[j] = vp[(size_t)j * QKV_N];
      }

      if (kt <= last_kt) {
        const bf16* kb = &Kb[cur][0];

        // ---- S^T = K Q^T : z[nt], lane = (q=l15, k=nt*16+l4*4+r), RAW ----
        f32x4 z[4];
        #pragma unroll
        for (int nt = 0; nt < 4; ++nt) z[nt] = (f32x4){0.f, 0.f, 0.f, 0.f};
        #pragma unroll
        for (int nt = 0; nt < 4; ++nt)
          #pragma unroll
          for (int kk = 0; kk < 2; ++kk) {
            bf16x8 kf = *(const bf16x8*)((const char*)kb +
                (((nt * 16 + l15) * 128 + (kk * 32 + l4 * 8) * 2) ^ ((l15 & 7) << 4)));
            z[nt] = __builtin_amdgcn_mfma_f32_16x16x32_bf16(kf, qf[kk], z[nt], 0, 0, 0);
          }

        if (kt == last_kt) {
          const int qg = qbase + l15;
          #pragma unroll
          for (int nt = 0; nt < 4; ++nt)
            #pragma unroll
            for (int r = 0; r < 4; ++r)
              if (kt * 64 + nt * 16 + l4 * 4 + r > qg) z[nt][r] = -INFINITY;
        }

        float vm = z[0][0];
        #pragma unroll
        for (int nt = 0; nt < 4; ++nt)
          #pragma unroll
          for (int r = 0; r < 4; ++r) vm = fmaxf(vm, z[nt][r]);
        vm = fmaxf(vm, __shfl_xor(vm, 16));
        vm = fmaxf(vm, __shfl_xor(vm, 32));

        if (!__all(vm - m_run <= THR_RAW)) {
          float mnew = fmaxf(m_run, vm);
          float alpha = __builtin_amdgcn_exp2f((m_run - mnew) * SCALE2);
          l_run *= alpha;
          #pragma unroll
          for (int dt = 0; dt < 4; ++dt)
            #pragma unroll
            for (int r = 0; r < 4; ++r) oacc[dt][r] *= alpha;
          m_run = mnew;
        }
        const float ms = m_run * SCALE2;

        float ps = 0.f;
        #pragma unroll
        for (int nt = 0; nt < 4; ++nt)
          #pragma unroll
          for (int r = 0; r < 4; ++r) {
            float pv = __builtin_amdgcn_exp2f(__builtin_fmaf(z[nt][r], SCALE2, -ms));
            z[nt][r] = pv;
            ps += pv;
          }
        ps += __shfl_xor(ps, 16);
        ps += __shfl_xor(ps, 32);
        l_run += ps;

        bf16* pbw = &Pb[wave][0];
        #pragma unroll
        for (int nt = 0; nt < 4; ++nt) {
          bf16x4 pk = { (bf16)z[nt][0], (bf16)z[nt][1], (bf16)z[nt][2], (bf16)z[nt][3] };
          *(bf16x4*)((char*)pbw + ((l15 * 128 + nt * 32 + l4 * 8) ^ ((l15 & 7) << 4))) = pk;
        }

        // ---- O^T += V^T P^T ----
        #pragma unroll
        for (int kk = 0; kk < 2; ++kk) {
          bf16x8 pf = *(const bf16x8*)((const char*)pbw +
              ((l15 * 128 + kk * 64 + l4 * 16) ^ ((l15 & 7) << 4)));
          #pragma unroll
          for (int dt = 0; dt < 4; ++dt) {
            bf16x8 vf = *(const bf16x8*)((const char*)&VTs[0] +
                (((dt * 16 + l15) * 128 + (kk * 32 + l4 * 8) * 2) ^ ((l15 & 7) << 4)));
            oacc[dt] = __builtin_amdgcn_mfma_f32_16x16x32_bf16(vf, pf, oacc[dt], 0, 0, 0);
          }
        }
      }

      if (has_next) {
        __syncthreads();   // all waves done reading VTs
        *(bf16x8*)((char*)&VTs[0] + ((lane * 128 + wave * 16) ^ ((lane & 7) << 4))) = vr;
        __syncthreads();   // VTs(t+1) visible; Kb[cur^1] glds landed
        cur ^= 1;
      }
    }

    // ---- epilogue: O^T -> y. q = qbase+l15, d = dt*16+l4*4+r ----
    {
      float linv = __builtin_amdgcn_rcpf(l_run);
      bf16* yp = y + ((size_t)b * T_SEQ + qbase + l15) * DIM + h * HD + l4 * 4;
      #pragma unroll
      for (int dt = 0; dt < 4; ++dt) {
        bf16x4 ov = { (bf16)(oacc[dt][0] * linv), (bf16)(oacc[dt][1] * linv),
                      (bf16)(oacc[dt][2] * linv), (bf16)(oacc[dt][3] * linv) };
        *(bf16x4*)(yp + dt * 16) = ov;
      }
    }
  }
}

// ---------------- launch ----------------
extern "C" void kernel_launch(void* const* d_in, const int* in_sizes, int n_in,
                              void* d_out, int out_size, void* d_ws, size_t ws_size,
                              hipStream_t stream) {
  const float* x    = (const float*)d_in[0];
  const float* cosb = (const float*)d_in[1];
  const float* sinb = (const float*)d_in[2];
  const float* wq   = (const float*)d_in[3];
  const float* wk   = (const float*)d_in[4];
  const float* wv   = (const float*)d_in[5];
  const float* wo   = (const float*)d_in[6];
  float* out = (float*)d_out;

  bf16* xb   = (bf16*)d_ws;                           // 4096*2048
  bf16* wqkv = xb + (size_t)MROWS * DIM;              // 3072*2048
  bf16* wob  = wqkv + (size_t)QKV_N * DIM;            // 2048*2048
  bf16* qkv  = wob + (size_t)DIM * DIM;               // 4096*3072
  bf16* y    = qkv + (size_t)MROWS * QKV_N;           // 4096*2048

  cast_kernel<<<2048, 256, 0, stream>>>(x, xb, MROWS * DIM);
  cast_w_kernel<<<2048, 256, 0, stream>>>(wq, wk, wv, wo, wqkv, wob);

  // QKV projection: M=4096, N=3072, K=2048 -> 384 blocks
  gemm256<bf16><<<384, 512, 0, stream>>>(xb, wqkv, qkv, QKV_N, DIM, 384 / 8);

  // RoPE on q,k
  rope_kernel<<<(MROWS * 160) / 256, 256, 0, stream>>>(qkv, cosb, sinb);

  // attention: 2 strips (15-p then p) per block -> uniform 34 tiles/block
  attn_kernel<<<dim3(NH, 8, 2), 512, 0, stream>>>(qkv, y);

  // output projection: M=4096, N=2048, K=2048 -> 256 blocks
  gemm256<float><<<256, 512, 0, stream>>>(y, wob, out, DIM, DIM, 256 / 8);
}

// Round 15
// 185.634 us; speedup vs baseline: 1.0544x; 1.0544x over previous
//
#include <hip/hip_runtime.h>

typedef __bf16 bf16;
typedef __attribute__((ext_vector_type(8))) __bf16 bf16x8;
typedef __attribute__((ext_vector_type(4))) __bf16 bf16x4;
typedef __attribute__((ext_vector_type(4))) float f32x4;

constexpr int T_SEQ = 2048;
constexpr int DIM   = 2048;
constexpr int NH    = 32;
constexpr int NKV   = 8;
constexpr int HD    = 64;
constexpr int QKV_N = DIM + 2 * NKV * HD;   // 3072
constexpr int MROWS = 2 * T_SEQ;            // 4096 (B*T)

// ---------------- cast f32 -> bf16 (x) ----------------
__global__ void cast_kernel(const float* __restrict__ in, bf16* __restrict__ out, int n) {
  int stride = gridDim.x * blockDim.x * 4;
  for (int i = (blockIdx.x * blockDim.x + threadIdx.x) * 4; i < n; i += stride) {
    float4 v = *(const float4*)(in + i);
    bf16x4 o = { (bf16)v.x, (bf16)v.y, (bf16)v.z, (bf16)v.w };
    *(bf16x4*)(out + i) = o;
  }
}

// ---------------- fused weight cast: wq|wk|wv -> wqkv, wo -> wob ----------------
__global__ void cast_w_kernel(const float* __restrict__ wq, const float* __restrict__ wk,
                              const float* __restrict__ wv, const float* __restrict__ wo,
                              bf16* __restrict__ wqkv, bf16* __restrict__ wob) {
  int stride = gridDim.x * blockDim.x;
  for (int g = blockIdx.x * blockDim.x + threadIdx.x; g < 2621440; g += stride) {
    const float* src; bf16* dst; int off;
    if (g < 1048576)      { src = wq; dst = wqkv;           off = g; }
    else if (g < 1310720) { src = wk; dst = wqkv + 4194304; off = g - 1048576; }
    else if (g < 1572864) { src = wv; dst = wqkv + 5242880; off = g - 1310720; }
    else                  { src = wo; dst = wob;            off = g - 1572864; }
    float4 v = *(const float4*)(src + (size_t)off * 4);
    bf16x4 o = { (bf16)v.x, (bf16)v.y, (bf16)v.z, (bf16)v.w };
    *(bf16x4*)(dst + (size_t)off * 4) = o;
  }
}

// ---------------- GEMM (unchanged R11: 3-deep ring, counted vmcnt(6)) ----------------
template <typename OutT>
__global__ __launch_bounds__(512) void gemm256(const bf16* __restrict__ A,
                                               const bf16* __restrict__ W,
                                               OutT* __restrict__ C,
                                               int N, int K, int cpx) {
  constexpr int BM = 256, BN = 128, BK = 64;
  __shared__ __attribute__((aligned(16))) bf16 Ab[3][BM * BK];
  __shared__ __attribute__((aligned(16))) bf16 Bb[3][BN * BK];
  const int tid = threadIdx.x, lane = tid & 63, wave = tid >> 6;
  const int l15 = lane & 15, l4 = lane >> 4;
  const int orig = blockIdx.x;
  const int wg = (orig & 7) * cpx + (orig >> 3);
  const int bm = (wg & 15) * BM;
  const int bn = (wg >> 4) * BN;
  const int wm = (wave >> 1) * 64, wn = (wave & 1) * 64;

  f32x4 acc[4][4] = {};

  const int NT = K / BK;
  auto stage = [&](int s, int k0) {
    #pragma unroll
    for (int i = 0; i < 4; ++i) {
      int c = i * 512 + tid;
      int row = c >> 3;
      int gc = ((c & 7) ^ (row & 7)) << 3;
      __builtin_amdgcn_global_load_lds(
          (const __attribute__((address_space(1))) unsigned int*)(A + (size_t)(bm + row) * K + k0 + gc),
          (__attribute__((address_space(3))) unsigned int*)(&Ab[s][0] + c * 8), 16, 0, 0);
    }
    #pragma unroll
    for (int i = 0; i < 2; ++i) {
      int c = i * 512 + tid;
      int row = c >> 3;
      int gc = ((c & 7) ^ (row & 7)) << 3;
      __builtin_amdgcn_global_load_lds(
          (const __attribute__((address_space(1))) unsigned int*)(W + (size_t)(bn + row) * K + k0 + gc),
          (__attribute__((address_space(3))) unsigned int*)(&Bb[s][0] + c * 8), 16, 0, 0);
    }
  };

  stage(0, 0);
  stage(1, BK);

  int d = 0;
  for (int t = 0; t < NT; ++t) {
    if (t + 1 < NT) { asm volatile("s_waitcnt vmcnt(6)" ::: "memory"); }
    else            { asm volatile("s_waitcnt vmcnt(0)" ::: "memory"); }
    __builtin_amdgcn_s_barrier();

    bf16x8 af[2][4], bfr[2][4];
    #pragma unroll
    for (int kk = 0; kk < 2; ++kk) {
      #pragma unroll
      for (int mi = 0; mi < 4; ++mi) {
        int row = wm + mi * 16 + l15;
        af[kk][mi] = *(const bf16x8*)((const char*)&Ab[d][0] + row * 128 +
                                      (((kk * 4 + l4) ^ (row & 7)) << 4));
      }
      #pragma unroll
      for (int ni = 0; ni < 4; ++ni) {
        int row = wn + ni * 16 + l15;
        bfr[kk][ni] = *(const bf16x8*)((const char*)&Bb[d][0] + row * 128 +
                                       (((kk * 4 + l4) ^ (row & 7)) << 4));
      }
    }

    if (t + 2 < NT) {
      int s = d + 2; if (s >= 3) s -= 3;
      stage(s, (t + 2) * BK);
    }

    __builtin_amdgcn_s_setprio(1);
    #pragma unroll
    for (int kk = 0; kk < 2; ++kk)
      #pragma unroll
      for (int mi = 0; mi < 4; ++mi)
        #pragma unroll
        for (int ni = 0; ni < 4; ++ni)
          acc[mi][ni] = __builtin_amdgcn_mfma_f32_16x16x32_bf16(af[kk][mi], bfr[kk][ni],
                                                                acc[mi][ni], 0, 0, 0);
    __builtin_amdgcn_s_setprio(0);

    ++d; if (d == 3) d = 0;
  }

  #pragma unroll
  for (int mi = 0; mi < 4; ++mi)
    #pragma unroll
    for (int ni = 0; ni < 4; ++ni) {
      size_t row = (size_t)bm + wm + mi * 16 + l4 * 4;
      int col = bn + wn + ni * 16 + l15;
      #pragma unroll
      for (int r = 0; r < 4; ++r)
        C[(row + r) * N + col] = (OutT)acc[mi][ni][r];
    }
}

// ---------------- RoPE, vectorized (unchanged) ----------------
__global__ void rope_kernel(bf16* __restrict__ qkv, const float* __restrict__ cs,
                            const float* __restrict__ sn) {
  int idx = blockIdx.x * blockDim.x + threadIdx.x;
  int m = idx / 160;
  int ch = idx - m * 160;
  int t = m & (T_SEQ - 1);
  int col, c;
  if (ch < 128) { int hh = ch >> 2; c = ch & 3; col = hh * 64 + c * 16; }
  else          { int ch2 = ch - 128; int hh = ch2 >> 2; c = ch2 & 3; col = DIM + hh * 64 + c * 16; }
  bf16* ptr = qkv + (size_t)m * QKV_N + col;
  bf16x8 v0 = *(bf16x8*)ptr, v1 = *(bf16x8*)(ptr + 8);
  const float* cp = cs + t * 32 + c * 8;
  const float* sp = sn + t * 32 + c * 8;
  float4 c0 = *(const float4*)cp, c1 = *(const float4*)(cp + 4);
  float4 s0 = *(const float4*)sp, s1 = *(const float4*)(sp + 4);
  float cc[8] = {c0.x, c0.y, c0.z, c0.w, c1.x, c1.y, c1.z, c1.w};
  float ss[8] = {s0.x, s0.y, s0.z, s0.w, s1.x, s1.y, s1.z, s1.w};
  bf16x8 o0, o1;
  #pragma unroll
  for (int j = 0; j < 4; ++j) {
    float a = (float)v0[2 * j], b = (float)v0[2 * j + 1];
    o0[2 * j]     = (bf16)(a * cc[j] - b * ss[j]);
    o0[2 * j + 1] = (bf16)(a * ss[j] + b * cc[j]);
  }
  #pragma unroll
  for (int j = 0; j < 4; ++j) {
    float a = (float)v1[2 * j], b = (float)v1[2 * j + 1];
    o1[2 * j]     = (bf16)(a * cc[4 + j] - b * ss[4 + j]);
    o1[2 * j + 1] = (bf16)(a * ss[4 + j] + b * cc[4 + j]);
  }
  *(bf16x8*)ptr = o0;
  *(bf16x8*)(ptr + 8) = o1;
}

// ---------------- Flash attention, causal GQA ----------------
// grid (NH, 16, B); 512 thr = 8 waves x 16 q-rows = ONE 128-row strip/block.
// KVBLK=128: K staged as one 128x64 dbuf tile (2 glds), V as two 64-kv halves
// (reg-gather, single-buffered, write-late). 2 barriers per 128 kv (was 4) ->
// half the lockstep sync events that bounded R13/R14. Waves 0-3 skip the
// fully-masked upper half of the diagonal tile. LDS 64KB -> 2 blocks/CU.
__global__ __launch_bounds__(512, 2) void attn_kernel(const bf16* __restrict__ qkv,
                                                      bf16* __restrict__ y) {
  const int h = blockIdx.x, b = blockIdx.z;
  const int strip = 15 - blockIdx.y;              // longest-first (LPT w/ backfill)
  const int g = h >> 2;
  const int tid = threadIdx.x, lane = tid & 63, wave = tid >> 6;
  const int l15 = lane & 15, l4 = lane >> 4;
  const int qbase = strip * 128 + wave * 16;

  __shared__ __attribute__((aligned(16))) bf16 Kb[2][128 * 64];  // [kv][d], swizzled, dbuf
  __shared__ __attribute__((aligned(16))) bf16 VTs[2][64 * 64];  // [d][kv] per half, swizzled
  __shared__ __attribute__((aligned(16))) bf16 Pb[8][16 * 64];   // per-wave [q][kv], swizzled

  constexpr float SCALE2 = 0.125f * 1.44269504088896f;
  constexpr float THR_RAW = 8.0f / SCALE2;
  constexpr int VOFF = DIM + NKV * HD;

  bf16x8 qf[2];
  {
    const bf16* qp = qkv + ((size_t)b * T_SEQ + qbase + l15) * QKV_N + h * HD + l4 * 8;
    qf[0] = *(const bf16x8*)(qp);
    qf[1] = *(const bf16x8*)(qp + 32);
  }

  f32x4 oacc[4] = {};
  float m_run = -INFINITY, l_run = 0.f;
  const int qg = qbase + l15;

  const int nt = strip + 1;                 // 128-kv tiles
  const size_t kvbase = (size_t)b * T_SEQ;

  // ---- prologue: K tile0 (2 glds) -> Kb[0]; V tile0 halves -> VTs ----
  {
    #pragma unroll
    for (int i = 0; i < 2; ++i) {
      int chunk = i * 512 + tid;
      int row = chunk >> 3;
      int csrc = ((chunk & 7) << 3) ^ ((row & 7) << 3);
      __builtin_amdgcn_global_load_lds(
          (const __attribute__((address_space(1))) unsigned int*)
              (qkv + (kvbase + row) * QKV_N + DIM + g * HD + csrc),
          (__attribute__((address_space(3))) unsigned int*)(&Kb[0][0] + chunk * 8), 16, 0, 0);
    }
    #pragma unroll
    for (int hf = 0; hf < 2; ++hf) {
      const bf16* vp = qkv + (kvbase + hf * 64 + wave * 8) * QKV_N + VOFF + g * HD + lane;
      bf16x8 vr;
      #pragma unroll
      for (int j = 0; j < 8; ++j) vr[j] = vp[(size_t)j * QKV_N];
      *(bf16x8*)((char*)&VTs[hf][0] + ((lane * 128 + wave * 16) ^ ((lane & 7) << 4))) = vr;
    }
    asm volatile("s_waitcnt vmcnt(0)" ::: "memory");
    __syncthreads();
  }

  int cur = 0;
  for (int kt = 0; kt < nt; ++kt) {
    const bool has_next = (kt + 1) < nt;
    bf16x8 vr0, vr1;
    if (has_next) {
      // issue next K tile (async -> Kb[cur^1])
      #pragma unroll
      for (int i = 0; i < 2; ++i) {
        int chunk = i * 512 + tid;
        int row = chunk >> 3;
        int csrc = ((chunk & 7) << 3) ^ ((row & 7) << 3);
        __builtin_amdgcn_global_load_lds(
            (const __attribute__((address_space(1))) unsigned int*)
                (qkv + (kvbase + (kt + 1) * 128 + row) * QKV_N + DIM + g * HD + csrc),
            (__attribute__((address_space(3))) unsigned int*)(&Kb[cur ^ 1][0] + chunk * 8), 16, 0, 0);
      }
      // issue next V gathers (regs; written to VTs after the tail barrier)
      const bf16* vp0 = qkv + (kvbase + (kt + 1) * 128 + wave * 8) * QKV_N + VOFF + g * HD + lane;
      const bf16* vp1 = vp0 + (size_t)64 * QKV_N;
      #pragma unroll
      for (int j = 0; j < 8; ++j) vr0[j] = vp0[(size_t)j * QKV_N];
      #pragma unroll
      for (int j = 0; j < 8; ++j) vr1[j] = vp1[(size_t)j * QKV_N];
    }

    const bf16* kb = &Kb[cur][0];
    const bool diag = (kt == strip);

    #pragma unroll
    for (int hf = 0; hf < 2; ++hf) {
      if (diag && hf == 1 && wave < 4) continue;   // fully-masked upper half

      // ---- S^T = K Q^T : z[nt4], lane = (q=l15, k=hf*64+nt4*16+l4*4+r), RAW ----
      f32x4 z[4];
      #pragma unroll
      for (int nt4 = 0; nt4 < 4; ++nt4) z[nt4] = (f32x4){0.f, 0.f, 0.f, 0.f};
      #pragma unroll
      for (int nt4 = 0; nt4 < 4; ++nt4)
        #pragma unroll
        for (int kk = 0; kk < 2; ++kk) {
          bf16x8 kf = *(const bf16x8*)((const char*)kb +
              (((hf * 64 + nt4 * 16 + l15) * 128 + (kk * 32 + l4 * 8) * 2) ^ ((l15 & 7) << 4)));
          z[nt4] = __builtin_amdgcn_mfma_f32_16x16x32_bf16(kf, qf[kk], z[nt4], 0, 0, 0);
        }

      if (diag) {
        #pragma unroll
        for (int nt4 = 0; nt4 < 4; ++nt4)
          #pragma unroll
          for (int r = 0; r < 4; ++r)
            if (kt * 128 + hf * 64 + nt4 * 16 + l4 * 4 + r > qg) z[nt4][r] = -INFINITY;
      }

      float vm = z[0][0];
      #pragma unroll
      for (int nt4 = 0; nt4 < 4; ++nt4)
        #pragma unroll
        for (int r = 0; r < 4; ++r) vm = fmaxf(vm, z[nt4][r]);
      vm = fmaxf(vm, __shfl_xor(vm, 16));
      vm = fmaxf(vm, __shfl_xor(vm, 32));

      if (!__all(vm - m_run <= THR_RAW)) {
        float mnew = fmaxf(m_run, vm);
        float alpha = __builtin_amdgcn_exp2f((m_run - mnew) * SCALE2);
        l_run *= alpha;
        #pragma unroll
        for (int dt = 0; dt < 4; ++dt)
          #pragma unroll
          for (int r = 0; r < 4; ++r) oacc[dt][r] *= alpha;
        m_run = mnew;
      }
      const float ms = m_run * SCALE2;

      float ps = 0.f;
      #pragma unroll
      for (int nt4 = 0; nt4 < 4; ++nt4)
        #pragma unroll
        for (int r = 0; r < 4; ++r) {
          float pv = __builtin_amdgcn_exp2f(__builtin_fmaf(z[nt4][r], SCALE2, -ms));
          z[nt4][r] = pv;
          ps += pv;
        }
      ps += __shfl_xor(ps, 16);
      ps += __shfl_xor(ps, 32);
      l_run += ps;

      bf16* pbw = &Pb[wave][0];
      #pragma unroll
      for (int nt4 = 0; nt4 < 4; ++nt4) {
        bf16x4 pk = { (bf16)z[nt4][0], (bf16)z[nt4][1], (bf16)z[nt4][2], (bf16)z[nt4][3] };
        *(bf16x4*)((char*)pbw + ((l15 * 128 + nt4 * 32 + l4 * 8) ^ ((l15 & 7) << 4))) = pk;
      }

      // ---- O^T += V^T P^T (this half) ----
      const bf16* vt = &VTs[hf][0];
      #pragma unroll
      for (int kk = 0; kk < 2; ++kk) {
        bf16x8 pf = *(const bf16x8*)((const char*)pbw +
            ((l15 * 128 + kk * 64 + l4 * 16) ^ ((l15 & 7) << 4)));
        #pragma unroll
        for (int dt = 0; dt < 4; ++dt) {
          bf16x8 vf = *(const bf16x8*)((const char*)vt +
              (((dt * 16 + l15) * 128 + (kk * 32 + l4 * 8) * 2) ^ ((l15 & 7) << 4)));
          oacc[dt] = __builtin_amdgcn_mfma_f32_16x16x32_bf16(vf, pf, oacc[dt], 0, 0, 0);
        }
      }
    }

    if (has_next) {
      __syncthreads();   // all waves done reading VTs (also drains K glds)
      *(bf16x8*)((char*)&VTs[0][0] + ((lane * 128 + wave * 16) ^ ((lane & 7) << 4))) = vr0;
      *(bf16x8*)((char*)&VTs[1][0] + ((lane * 128 + wave * 16) ^ ((lane & 7) << 4))) = vr1;
      __syncthreads();   // VTs(t+1) visible; Kb[cur^1] landed
      cur ^= 1;
    }
  }

  // ---- epilogue: O^T -> y. q = qbase+l15, d = dt*16+l4*4+r ----
  {
    float linv = __builtin_amdgcn_rcpf(l_run);
    bf16* yp = y + ((size_t)b * T_SEQ + qbase + l15) * DIM + h * HD + l4 * 4;
    #pragma unroll
    for (int dt = 0; dt < 4; ++dt) {
      bf16x4 ov = { (bf16)(oacc[dt][0] * linv), (bf16)(oacc[dt][1] * linv),
                    (bf16)(oacc[dt][2] * linv), (bf16)(oacc[dt][3] * linv) };
      *(bf16x4*)(yp + dt * 16) = ov;
    }
  }
}

// ---------------- launch ----------------
extern "C" void kernel_launch(void* const* d_in, const int* in_sizes, int n_in,
                              void* d_out, int out_size, void* d_ws, size_t ws_size,
                              hipStream_t stream) {
  const float* x    = (const float*)d_in[0];
  const float* cosb = (const float*)d_in[1];
  const float* sinb = (const float*)d_in[2];
  const float* wq   = (const float*)d_in[3];
  const float* wk   = (const float*)d_in[4];
  const float* wv   = (const float*)d_in[5];
  const float* wo   = (const float*)d_in[6];
  float* out = (float*)d_out;

  bf16* xb   = (bf16*)d_ws;                           // 4096*2048
  bf16* wqkv = xb + (size_t)MROWS * DIM;              // 3072*2048
  bf16* wob  = wqkv + (size_t)QKV_N * DIM;            // 2048*2048
  bf16* qkv  = wob + (size_t)DIM * DIM;               // 4096*3072
  bf16* y    = qkv + (size_t)MROWS * QKV_N;           // 4096*2048

  cast_kernel<<<2048, 256, 0, stream>>>(x, xb, MROWS * DIM);
  cast_w_kernel<<<2048, 256, 0, stream>>>(wq, wk, wv, wo, wqkv, wob);

  // QKV projection: M=4096, N=3072, K=2048 -> 384 blocks
  gemm256<bf16><<<384, 512, 0, stream>>>(xb, wqkv, qkv, QKV_N, DIM, 384 / 8);

  // RoPE on q,k
  rope_kernel<<<(MROWS * 160) / 256, 256, 0, stream>>>(qkv, cosb, sinb);

  // attention: one 128-row strip per block, KVBLK=128 (2 barriers/128kv)
  attn_kernel<<<dim3(NH, 16, 2), 512, 0, stream>>>(qkv, y);

  // output projection: M=4096, N=2048, K=2048 -> 256 blocks
  gemm256<float><<<256, 512, 0, stream>>>(y, wob, out, DIM, DIM, 256 / 8);
}